// Round 1
// baseline (163.380 us; speedup 1.0000x reference)
//
#include <hip/hip_runtime.h>
#include <stdint.h>

#define V_DIM 32000
#define M_TOT 4096      // B*S = 2*2048
#define NF 128          // 2*n_freq
#define NC 256          // channels
#define BM 128
#define BK 32
#define KGN 4           // BK/8
#define SLOT_STRIDE 129 // 128 rows + 1 pad slot per kg-plane
#define NSLOT (KGN * SLOT_STRIDE)
#define THREADS 256
#define MAX_SPLITS 16

typedef __bf16 bf16x8 __attribute__((ext_vector_type(8)));
typedef float f32x4 __attribute__((ext_vector_type(4)));

__device__ __forceinline__ unsigned short f2bf(float f) {
  // round-to-nearest-even fp32 -> bf16 (inputs are finite)
  unsigned int u = __float_as_uint(f);
  u += 0x7FFFu + ((u >> 16) & 1u);
  return (unsigned short)(u >> 16);
}

// ---------------- Stage 0: DFT basis table, bf16 [NF][V] ----------------
// T[f][v] = cos(2*pi*(f+1)*v/V)        f in [0,64)
// T[64+g][v] = -sin(2*pi*(g+1)*v/V)    g in [0,64)
__global__ void build_table(unsigned short* __restrict__ T) {
  int v = blockIdx.x * blockDim.x + threadIdx.x;
  if (v >= V_DIM) return;
  const float w0 = 6.283185307179586f / (float)V_DIM;
  #pragma unroll 4
  for (int k = 1; k <= 64; ++k) {
    int m = (k * v) % V_DIM;   // exact range reduction
    float s, c;
    __sincosf((float)m * w0, &s, &c);
    T[(size_t)(k - 1) * V_DIM + v] = f2bf(c);
    T[(size_t)(63 + k) * V_DIM + v] = f2bf(-s);
  }
}

// ---------------- Stage 1: X_partial[ks] = x_chunk @ T_chunk^T ----------------
__global__ __launch_bounds__(THREADS) void gemm1(
    const float* __restrict__ x, const unsigned short* __restrict__ T,
    float* __restrict__ P, int NS) {
  __shared__ __align__(16) unsigned short As[2][NSLOT * 8];
  __shared__ __align__(16) unsigned short Bs[2][NSLOT * 8];

  const int mt = blockIdx.x;          // 0..31
  const int ks = blockIdx.y;          // 0..NS-1
  const int m0 = mt * BM;

  const int total_steps = V_DIM / BK; // 1000
  const int base = total_steps / NS;
  const int rem = total_steps % NS;
  const int steps = base + (ks < rem ? 1 : 0);
  const int start = ks * base + (ks < rem ? ks : rem);
  const int vbase = start * BK;       // element offset in V

  const int t = threadIdx.x;
  const int lane = t & 63;
  const int wave = t >> 6;
  const int wm = wave >> 1, wn = wave & 1;

  // staging assignment: thread -> (kg, row) and (kg, row+64)
  const int kg_t = t & 3;
  const int row_t = t >> 2;           // 0..63
  const int slot0 = kg_t * SLOT_STRIDE + row_t;
  const int slot1 = slot0 + 64;

  const float* xa0 = x + (size_t)(m0 + row_t) * V_DIM + kg_t * 8;
  const float* xa1 = xa0 + (size_t)64 * V_DIM;
  const unsigned short* tb0 = T + (size_t)row_t * V_DIM + kg_t * 8;
  const unsigned short* tb1 = tb0 + (size_t)64 * V_DIM;

  f32x4 acc[4][4];
  #pragma unroll
  for (int i = 0; i < 4; ++i)
    #pragma unroll
    for (int j = 0; j < 4; ++j)
      acc[i][j] = (f32x4){0.f, 0.f, 0.f, 0.f};

  auto pack8 = [](float4 lo, float4 hi) -> int4 {
    union { unsigned short us[8]; int4 v; } u;
    u.us[0] = f2bf(lo.x); u.us[1] = f2bf(lo.y);
    u.us[2] = f2bf(lo.z); u.us[3] = f2bf(lo.w);
    u.us[4] = f2bf(hi.x); u.us[5] = f2bf(hi.y);
    u.us[6] = f2bf(hi.z); u.us[7] = f2bf(hi.w);
    return u.v;
  };

  auto stage = [&](int buf, int vabs) {
    float4 a0 = *reinterpret_cast<const float4*>(xa0 + vabs);
    float4 a1 = *reinterpret_cast<const float4*>(xa0 + vabs + 4);
    float4 a2 = *reinterpret_cast<const float4*>(xa1 + vabs);
    float4 a3 = *reinterpret_cast<const float4*>(xa1 + vabs + 4);
    int4 b0 = *reinterpret_cast<const int4*>(tb0 + vabs);
    int4 b1 = *reinterpret_cast<const int4*>(tb1 + vabs);
    *reinterpret_cast<int4*>(&As[buf][slot0 * 8]) = pack8(a0, a1);
    *reinterpret_cast<int4*>(&As[buf][slot1 * 8]) = pack8(a2, a3);
    *reinterpret_cast<int4*>(&Bs[buf][slot0 * 8]) = b0;
    *reinterpret_cast<int4*>(&Bs[buf][slot1 * 8]) = b1;
  };

  // prologue
  stage(0, vbase);
  __syncthreads();

  const int kgl = lane >> 4;   // 0..3 (k-group)
  const int rl = lane & 15;    // row/col within fragment

  for (int s = 0; s < steps; ++s) {
    const int cur = s & 1;
    const int nxt = cur ^ 1;
    if (s + 1 < steps) stage(nxt, vbase + (s + 1) * BK);

    bf16x8 af[4], bfv[4];
    #pragma unroll
    for (int mf = 0; mf < 4; ++mf) {
      int slot = kgl * SLOT_STRIDE + wm * 64 + mf * 16 + rl;
      af[mf] = *reinterpret_cast<const bf16x8*>(&As[cur][slot * 8]);
    }
    #pragma unroll
    for (int nf = 0; nf < 4; ++nf) {
      int slot = kgl * SLOT_STRIDE + wn * 64 + nf * 16 + rl;
      bfv[nf] = *reinterpret_cast<const bf16x8*>(&Bs[cur][slot * 8]);
    }
    #pragma unroll
    for (int mf = 0; mf < 4; ++mf)
      #pragma unroll
      for (int nf = 0; nf < 4; ++nf)
        acc[mf][nf] = __builtin_amdgcn_mfma_f32_16x16x32_bf16(
            af[mf], bfv[nf], acc[mf][nf], 0, 0, 0);

    __syncthreads();
  }

  // epilogue: write partial tile [128 x 128] for this k-split
  float* Pp = P + ((size_t)ks * M_TOT + m0) * NF;
  const int r0 = (lane >> 4) * 4;
  const int col = lane & 15;
  #pragma unroll
  for (int mf = 0; mf < 4; ++mf)
    #pragma unroll
    for (int nf = 0; nf < 4; ++nf)
      #pragma unroll
      for (int j = 0; j < 4; ++j) {
        int row = wm * 64 + mf * 16 + r0 + j;
        int n = wn * 64 + nf * 16 + col;
        Pp[(size_t)row * NF + n] = acc[mf][nf][j];
      }
}

// ---------------- Stage 2: out = (sum_s P[s]) @ W^T ----------------
__global__ __launch_bounds__(256) void gemm2(
    const float* __restrict__ P, const float* __restrict__ W,
    float* __restrict__ out, int NS) {
  __shared__ __align__(16) float Xr[8][NF];
  const int mb = blockIdx.x * 8;
  const int t = threadIdx.x;

  #pragma unroll
  for (int i = 0; i < 4; ++i) {
    int idx = t + i * 256;           // 0..1023
    int r = idx >> 7, f = idx & 127;
    float s = 0.f;
    for (int sp = 0; sp < NS; ++sp)
      s += P[((size_t)sp * M_TOT + mb + r) * NF + f];
    Xr[r][f] = s;
  }
  __syncthreads();

  const float4* Wr = reinterpret_cast<const float4*>(W + (size_t)t * NF);
  float accr[8];
  #pragma unroll
  for (int r = 0; r < 8; ++r) accr[r] = 0.f;

  for (int f4 = 0; f4 < NF / 4; ++f4) {
    float4 w = Wr[f4];
    #pragma unroll
    for (int r = 0; r < 8; ++r) {
      float4 xv = *reinterpret_cast<const float4*>(&Xr[r][f4 * 4]);
      accr[r] += xv.x * w.x + xv.y * w.y + xv.z * w.z + xv.w * w.w;
    }
  }
  #pragma unroll
  for (int r = 0; r < 8; ++r)
    out[(size_t)(mb + r) * NC + t] = accr[r];
}

extern "C" void kernel_launch(void* const* d_in, const int* in_sizes, int n_in,
                              void* d_out, int out_size, void* d_ws, size_t ws_size,
                              hipStream_t stream) {
  const float* x = (const float*)d_in[0];
  const float* w = (const float*)d_in[1];
  float* out = (float*)d_out;

  unsigned short* T = (unsigned short*)d_ws;
  const size_t t_bytes = (size_t)NF * V_DIM * sizeof(unsigned short); // 8,192,000 (256-mult)
  float* P = (float*)((char*)d_ws + t_bytes);
  const size_t p_split_bytes = (size_t)M_TOT * NF * sizeof(float);    // 2 MiB per split

  int NS = MAX_SPLITS;
  if (ws_size < t_bytes + (size_t)MAX_SPLITS * p_split_bytes) {
    size_t avail = ws_size > t_bytes ? ws_size - t_bytes : 0;
    NS = (int)(avail / p_split_bytes);
    if (NS < 1) NS = 1;
    if (NS > MAX_SPLITS) NS = MAX_SPLITS;
  }

  build_table<<<dim3(V_DIM / 256), dim3(256), 0, stream>>>(T);
  gemm1<<<dim3(M_TOT / BM, NS), dim3(THREADS), 0, stream>>>(x, T, P, NS);
  gemm2<<<dim3(M_TOT / 8), dim3(256), 0, stream>>>(P, w, out, NS);
}